// Round 1
// 144.857 us; speedup vs baseline: 1.0685x; 1.0685x over previous
//
#include <hip/hip_runtime.h>
#include <math.h>

#define DD 256

typedef float  f32x4  __attribute__((ext_vector_type(4)));
typedef short  bf16x8 __attribute__((ext_vector_type(8)));

__device__ __forceinline__ unsigned short f2bf(float f) {
    unsigned int u = __float_as_uint(f);
    u = (u + 0x7fffu + ((u >> 16) & 1u)) >> 16;  // RNE
    return (unsigned short)u;
}
__device__ __forceinline__ float bf2f(unsigned int h16) {
    return __uint_as_float(h16 << 16);
}

// ---------------------------------------------------------------------------
// Fused prep: blocks [0,192) repack weights fp32->bf16 into MFMA-fragment-
// linear order (unchanged layout:
//   wall[mat][wb][k0][nt][lane] : 16 B holding
//   W_bt[n = wb*64 + nt*16 + (lane&15)][k = k0*32 + (lane>>4)*8 .. +8]).
// Blocks 192,193 compute the universal-layer p vectors
// (uniform state is preserved by the circulant update -> s0 = 0.0625*prod cos,
// verified in earlier rounds). Merged to save one serialized dispatch.
// ---------------------------------------------------------------------------
__global__ __launch_bounds__(256)
void prep_all(const float* __restrict__ w0, const float* __restrict__ w1,
              const float* __restrict__ cw1, const float* __restrict__ w2,
              const float* __restrict__ cw2, const float* __restrict__ wo,
              const float* __restrict__ u1_w, const float* __restrict__ u2_w,
              unsigned short* __restrict__ wall, float* __restrict__ p_out) {
    if (blockIdx.x >= 192) {
        const int j = threadIdx.x;
        const int which = blockIdx.x - 192;
        const float* uw = which ? u2_w : u1_w;
        float s = 0.0625f;  // 1/sqrt(256)
#pragma unroll
        for (int d = 0; d < 9; ++d)
#pragma unroll
            for (int g = 0; g < 3; ++g)
                s *= cosf(uw[d * DD * DD + j * DD + g]);
        p_out[which * DD + j] = s * s;
        return;
    }
    const int gid  = blockIdx.x * 256 + threadIdx.x;
    const int mat  = gid >> 13;
    const int rem  = gid & 8191;
    const int wb   = rem >> 11;
    const int rem2 = rem & 2047;
    const int k0   = rem2 >> 8;
    const int rem3 = rem2 & 255;
    const int nt   = rem3 >> 6;
    const int lane = rem3 & 63;
    const int n  = wb * 64 + nt * 16 + (lane & 15);
    const int kb = k0 * 32 + (lane >> 4) * 8;

    const float* src;
    bool tr = false;
    switch (mat) {
        case 0: src = w0; break;
        case 1: src = w1; break;
        case 2: src = cw1; tr = true; break;
        case 3: src = w2; break;
        case 4: src = cw2; tr = true; break;
        default: src = wo; break;
    }
    unsigned short tmp[8];
#pragma unroll
    for (int j = 0; j < 8; ++j) {
        const float v = tr ? src[(kb + j) * DD + n] : src[n * DD + kb + j];
        tmp[j] = f2bf(v);
    }
    *(uint4*)&wall[mat * 65536 + wb * 16384 + k0 * 2048 + nt * 512 + lane * 8] =
        *(const uint4*)tmp;
}

// ---------------------------------------------------------------------------
// LDS activation layout (now 64 rows): 16 B chunk (m, kc) at
// kc*64 + (m ^ (kc&7)). Same per-16-lane bank pattern as the verified 32-row
// version (kc stride 64 instead of 32; xor still within the low 3 bits of m).
// ---------------------------------------------------------------------------
__device__ __forceinline__ int chunk_idx(int m, int kc) {
    return kc * 64 + (m ^ (kc & 7));
}

__device__ __forceinline__ float fast_tanh(float x) {
    const float e = __expf(2.0f * x);
    return 1.0f - 2.0f * __builtin_amdgcn_rcpf(1.0f + e);
}

// lgkm-only barrier: drains LDS ops for cross-wave visibility but leaves
// global (W-prefetch) loads in flight across the layer boundary.
// (__syncthreads would emit s_waitcnt vmcnt(0) and kill the W pipeline.)
__device__ __forceinline__ void lds_barrier() {
    asm volatile("s_waitcnt lgkmcnt(0)" ::: "memory");
    __builtin_amdgcn_s_barrier();
}

// ---------------------------------------------------------------------------
// One fused layer, in-place activations, 64 rows / block, 8 waves.
// Wave w owns n in [32w, 32w+32) x all 64 m rows: nt=2, mt=4.
//   -> W traffic per FLOP halved vs 32-row blocks (each W frag feeds 4 m-frags)
// W ring depth 4, prefetch distance 3 (8 steps % 4 == 0 so slot parity is
// layer-invariant; steps 5..7 prime next layer's slots 0..2).
// A <- W rows (n), B <- h rows (m); D: row(quad*4+r) -> n, col(lane&15) -> m.
// ---------------------------------------------------------------------------
template <int MODE>  // 0: relu, 1: tanh(+p)
__device__ __forceinline__ void layer_step(uint4* h, bf16x8 (&wr)[4][2],
                                           const unsigned short* __restrict__ W,
                                           const unsigned short* __restrict__ Wn,
                                           const float* __restrict__ bias,
                                           const float* __restrict__ pv) {
    const int tid  = threadIdx.x;
    const int wv   = tid >> 6;
    const int lane = tid & 63;
    const int quad = lane >> 4;
    const int l15  = lane & 15;

    f32x4 acc[2][4];  // [nt][mt]
#pragma unroll
    for (int nt = 0; nt < 2; ++nt)
#pragma unroll
        for (int mt = 0; mt < 4; ++mt) acc[nt][mt] = (f32x4){0.f, 0.f, 0.f, 0.f};

    bf16x8 h_f[2][4];
#pragma unroll
    for (int mt = 0; mt < 4; ++mt)  // k0 = 0 fragments (kc = quad)
        h_f[0][mt] = *(const bf16x8*)&h[chunk_idx(mt * 16 + l15, quad)];

#pragma unroll
    for (int k0 = 0; k0 < 8; ++k0) {
        {   // prefetch W frags for step k0+3 (ring depth 4, distance 3)
            const int t = k0 + 3;
            const unsigned short* ws = (t < 8) ? &W[t * 2048] : &Wn[(t - 8) * 2048];
#pragma unroll
            for (int nt = 0; nt < 2; ++nt)
                wr[t & 3][nt] = *(const bf16x8*)&ws[nt * 512];
        }
        if (k0 < 7) {
            const int kc = (k0 + 1) * 4 + quad;
#pragma unroll
            for (int mt = 0; mt < 4; ++mt)
                h_f[(k0 + 1) & 1][mt] = *(const bf16x8*)&h[chunk_idx(mt * 16 + l15, kc)];
        }
#pragma unroll
        for (int nt = 0; nt < 2; ++nt)
#pragma unroll
            for (int mt = 0; mt < 4; ++mt)
                acc[nt][mt] = __builtin_amdgcn_mfma_f32_16x16x32_bf16(
                    wr[k0 & 3][nt], h_f[k0 & 1][mt], acc[nt][mt], 0, 0, 0);
    }

    // bias (+p) fetch issued before the barrier so latency hides under it
    const int nb = wv * 32;
    f32x4 addv[2];
#pragma unroll
    for (int nt = 0; nt < 2; ++nt) {
        const int n0 = nb + nt * 16 + quad * 4;
        addv[nt] = *(const f32x4*)&bias[n0];
        if (MODE == 1) addv[nt] += *(const f32x4*)&pv[n0];
    }

    lds_barrier();  // all reads of h done -> safe to overwrite in place

#pragma unroll
    for (int nt = 0; nt < 2; ++nt) {
        const int n0   = nb + nt * 16 + quad * 4;
        const int kc_o = n0 >> 3;
        const int half = quad & 1;
#pragma unroll
        for (int mt = 0; mt < 4; ++mt) {
            const f32x4 v = acc[nt][mt] + addv[nt];
            float t0, t1, t2, t3;
            if (MODE == 1) {
                t0 = fast_tanh(v.x); t1 = fast_tanh(v.y);
                t2 = fast_tanh(v.z); t3 = fast_tanh(v.w);
            } else {
                t0 = fmaxf(v.x, 0.f); t1 = fmaxf(v.y, 0.f);
                t2 = fmaxf(v.z, 0.f); t3 = fmaxf(v.w, 0.f);
            }
            uint2 u;
            u.x = (unsigned int)f2bf(t0) | ((unsigned int)f2bf(t1) << 16);
            u.y = (unsigned int)f2bf(t2) | ((unsigned int)f2bf(t3) << 16);
            *(uint2*)((char*)&h[chunk_idx(mt * 16 + l15, kc_o)] + half * 8) = u;
        }
    }

    lds_barrier();  // writes visible for next layer; W prefetch stays in flight
}

__global__ __launch_bounds__(512, 4)
void unet_fused(const float* __restrict__ x,
                const unsigned short* __restrict__ wall,
                const float* __restrict__ b0, const float* __restrict__ b1,
                const float* __restrict__ cb1, const float* __restrict__ b2,
                const float* __restrict__ cb2, const float* __restrict__ bo,
                const float* __restrict__ pbuf,
                float* __restrict__ out) {
    __shared__ uint4 h[2048];  // 32 KB: 64 rows x 256 bf16, chunked+swizzled
    const int m0   = blockIdx.x * 64;
    const int tid  = threadIdx.x;
    const int wv   = tid >> 6;
    const int lane = tid & 63;

    // this wave's fragment base inside any W matrix (32-n slice of old wb)
    const unsigned short* WB =
        wall + (wv >> 1) * 16384 + (wv & 1) * 1024 + lane * 8;

    // prime W ring slots 0..2 with layer-0 steps 0..2 BEFORE x staging
    bf16x8 wr[4][2];
#pragma unroll
    for (int t = 0; t < 3; ++t)
#pragma unroll
        for (int nt = 0; nt < 2; ++nt)
            wr[t][nt] = *(const bf16x8*)&WB[t * 2048 + nt * 512];

    // stage x (fp32, coalesced reads) -> h (bf16 chunks), 8 rows per wave
    const int c4     = tid & 63;       // float4 column index (k = c4*4)
    const int rbase  = wv * 8;
    const int kc_s   = c4 >> 1;
    const int half_s = c4 & 1;
#pragma unroll
    for (int i = 0; i < 8; ++i) {
        const int row = rbase + i;
        const float4 v = *(const float4*)&x[(size_t)(m0 + row) * DD + c4 * 4];
        uint2 u;
        u.x = (unsigned int)f2bf(v.x) | ((unsigned int)f2bf(v.y) << 16);
        u.y = (unsigned int)f2bf(v.z) | ((unsigned int)f2bf(v.w) << 16);
        *(uint2*)((char*)&h[chunk_idx(row, kc_s)] + half_s * 8) = u;
    }
    lds_barrier();

    layer_step<0>(h, wr, WB + 0 * 65536, WB + 1 * 65536, b0, nullptr);
    layer_step<0>(h, wr, WB + 1 * 65536, WB + 2 * 65536, b1, nullptr);
    layer_step<1>(h, wr, WB + 2 * 65536, WB + 3 * 65536, cb1, pbuf);
    layer_step<0>(h, wr, WB + 3 * 65536, WB + 4 * 65536, b2, nullptr);
    layer_step<1>(h, wr, WB + 4 * 65536, WB + 5 * 65536, cb2, pbuf + 256);
    layer_step<0>(h, wr, WB + 5 * 65536, WB + 0 * 65536, bo, nullptr);

    // final activations (bf16) -> fp32, coalesced float4 stores
#pragma unroll
    for (int i = 0; i < 8; ++i) {
        const int row = rbase + i;
        const uint2 u =
            *(const uint2*)((char*)&h[chunk_idx(row, kc_s)] + half_s * 8);
        float4 v;
        v.x = bf2f(u.x & 0xffffu); v.y = bf2f(u.x >> 16);
        v.z = bf2f(u.y & 0xffffu); v.w = bf2f(u.y >> 16);
        *(float4*)&out[(size_t)(m0 + row) * DD + c4 * 4] = v;
    }
}

// ---------------------------------------------------------------------------
extern "C" void kernel_launch(void* const* d_in, const int* in_sizes, int n_in,
                              void* d_out, int out_size, void* d_ws, size_t ws_size,
                              hipStream_t stream) {
    const float* x      = (const float*)d_in[0];
    const float* lin0_w = (const float*)d_in[1];
    const float* lin0_b = (const float*)d_in[2];
    const float* lin1_w = (const float*)d_in[3];
    const float* lin1_b = (const float*)d_in[4];
    const float* u1_w   = (const float*)d_in[5];
    const float* u1_cw  = (const float*)d_in[6];
    const float* u1_cb  = (const float*)d_in[7];
    const float* lin2_w = (const float*)d_in[8];
    const float* lin2_b = (const float*)d_in[9];
    const float* u2_w   = (const float*)d_in[10];
    const float* u2_cw  = (const float*)d_in[11];
    const float* u2_cb  = (const float*)d_in[12];
    const float* lino_w = (const float*)d_in[13];
    const float* lino_b = (const float*)d_in[14];

    float* out = (float*)d_out;
    unsigned short* wall = (unsigned short*)d_ws;         // 6*65536 bf16 = 768 KB
    float* pbuf = (float*)((char*)d_ws + 6 * 65536 * 2);  // 512 floats

    prep_all<<<dim3(194), dim3(256), 0, stream>>>(
        lin0_w, lin1_w, u1_cw, lin2_w, u2_cw, lino_w, u1_w, u2_w, wall, pbuf);
    unet_fused<<<dim3(512), dim3(512), 0, stream>>>(
        x, wall, lin0_b, lin1_b, u1_cb, lin2_b, u2_cb, lino_b, pbuf, out);
}